// Round 6
// baseline (2691.090 us; speedup 1.0000x reference)
//
#include <hip/hip_runtime.h>
#include <hip/hip_bf16.h>
#include <math.h>

typedef __hip_bfloat16 bf16;

#define NUSR 50000
#define NENT 100000
#define CC   64
#define EE   1500000
#define NNZI 1000000
#define NF_  4
#define R1_  15
#define R2_  47
#define NCH_E 98      /* ceil(100000/1024) scan chunks */
#define NCH_U 49      /* ceil(50000/1024) */
#define NCH   147
#define NB_E  196     /* ceil(100000/512) buckets */
#define NB_U  98      /* ceil(50000/512) */

__device__ __forceinline__ float b2f(bf16 x){ return __bfloat162float(x); }
__device__ __forceinline__ bf16  f2b(float x){ return __float2bfloat16(x); }
__device__ __forceinline__ float fin(float x){ return (x==x && fabsf(x) < 1e30f) ? x : 0.f; }

__device__ __forceinline__ float ldv(const float* p, long long i){ return p[i]; }
__device__ __forceinline__ float ldv(const bf16*  p, long long i){ return b2f(p[i]); }

struct LatArgs {
    const float *lin, *W1, *b1, *W2, *b2, *Wua, *bua, *Wwa, *bwa, *wt;
    float *lat, *nlat, *P2, *q2;
    int R;
};

// ---------------------------------------------------------------- sentinel
__global__ void k_sentinel(float* out, float v){ out[threadIdx.x] = v; }

// ---------------------------------------------------------------- init
__global__ void k_init(int* deg_e, int* deg_u, int* cur_e, int* cur_u, int* bcur){
    int i = blockIdx.x*256 + threadIdx.x;
    if (i < NENT){ deg_e[i] = 0; cur_e[i] = 0; }
    if (i < NUSR){ deg_u[i] = 0; cur_u[i] = 0; }
    if (i < NB_E + NB_U) bcur[i] = 0;
}

// ---------------------------------------------------------------- fp32 -> bf16 entity table
__global__ void k_conv(const float* __restrict__ src, bf16* __restrict__ dst){
    int i = blockIdx.x*256 + threadIdx.x;
    if (i < NENT*CC) dst[i] = f2b(src[i]);
}

// ---------------------------------------------------------------- histogram
__global__ void k_hist(const int* __restrict__ head, const int* __restrict__ irows,
                       int* deg_e, int* deg_u){
    int i = blockIdx.x*256 + threadIdx.x;
    if (i < EE){
        int h = head[i]; if ((unsigned)h < NENT) atomicAdd(&deg_e[h], 1);
    } else {
        int j = i - EE;
        if (j < NNZI){ int r = irows[j]; if ((unsigned)r < NUSR) atomicAdd(&deg_u[r], 1); }
    }
}

// ---------------------------------------------------------------- ordered scan (3 kernels)
__global__ void k_scan1(const int* __restrict__ deg_e, const int* __restrict__ deg_u, int* part){
    int b = blockIdx.x, t = threadIdx.x;
    const int* src; int n, base;
    if (b < NCH_E){ src = deg_e; n = NENT; base = b*1024; }
    else          { src = deg_u; n = NUSR; base = (b-NCH_E)*1024; }
    int s = 0;
    #pragma unroll
    for (int k = 0; k < 4; k++){ int idx = base + t*4 + k; if (idx < n) s += src[idx]; }
    __shared__ int red[256];
    red[t] = s; __syncthreads();
    for (int off = 128; off; off >>= 1){ if (t < off) red[t] += red[t+off]; __syncthreads(); }
    if (t == 0) part[b] = red[0];
}

__global__ void k_scan2(int* part){
    if (threadIdx.x == 0 && blockIdx.x == 0){
        int run = 0;
        for (int b = 0; b < NCH_E; b++){ int v = part[b]; part[b] = run; run += v; }
        run = 0;
        for (int b = NCH_E; b < NCH; b++){ int v = part[b]; part[b] = run; run += v; }
    }
}

__global__ void k_scan3(const int* __restrict__ deg_e, const int* __restrict__ deg_u,
                        const int* __restrict__ part,
                        unsigned* rsdeg_e, unsigned* rsdeg_u){
    int b = blockIdx.x, t = threadIdx.x;
    const int* src; int n, base; bool ent = (b < NCH_E);
    if (ent){ src = deg_e; n = NENT; base = b*1024; }
    else    { src = deg_u; n = NUSR; base = (b-NCH_E)*1024; }
    int v[4], d[4]; int s = 0;
    #pragma unroll
    for (int k = 0; k < 4; k++){
        int idx = base + t*4 + k;
        int x = (idx < n) ? src[idx] : 0;
        v[k] = s; d[k] = x; s += x;
    }
    __shared__ int red[256];
    red[t] = s; __syncthreads();
    for (int off = 1; off < 256; off <<= 1){
        int x = (t >= off) ? red[t-off] : 0;
        __syncthreads();
        red[t] += x;
        __syncthreads();
    }
    int excl = red[t] - s + part[b];
    #pragma unroll
    for (int k = 0; k < 4; k++){
        int idx = base + t*4 + k;
        if (idx < n){
            int rs = excl + v[k];
            if (ent){
                int dc = d[k] < 2047 ? d[k] : 2047;
                rsdeg_e[idx] = ((unsigned)rs & 0x1FFFFFu) | ((unsigned)dc << 21);
            } else {
                int dc = d[k] < 4095 ? d[k] : 4095;
                rsdeg_u[idx] = ((unsigned)rs & 0xFFFFFu) | ((unsigned)dc << 20);
            }
        }
    }
}

// ---------------------------------------------------------------- binned scatter pass 1 (dense appends)
// epk payload: tail(17) | rel(4)<<17 | cate(5)<<21 ; upk payload: col(17) | bf16val(15)<<17
__global__ void k_scat1(const int* __restrict__ head, const int* __restrict__ tail,
                        const int* __restrict__ etype, const int* __restrict__ cate,
                        const int* __restrict__ irows, const int* __restrict__ icols,
                        const float* __restrict__ ivals,
                        const unsigned* __restrict__ rsdeg_e, const unsigned* __restrict__ rsdeg_u,
                        int* bcur, uint2* bin_e, uint2* bin_u){
    int i = blockIdx.x*256 + threadIdx.x;
    if (i < EE){
        int h = head[i]; if ((unsigned)h >= NENT) return;
        unsigned tu = (unsigned)tail[i]; if (tu >= NENT) tu = 0;
        unsigned ty = (unsigned)(etype[i] - 1) & 15u;
        unsigned cd = (unsigned)(cate[tu]  - 1) & 31u;
        unsigned pay = tu | (ty << 17) | (cd << 21);
        int b = h >> 9;
        unsigned bb = rsdeg_e[b << 9] & 0x1FFFFFu;    // bucket base = rs of first row (scan is ordered)
        unsigned slot = bb + (unsigned)atomicAdd(&bcur[b], 1);
        if (slot < EE) bin_e[slot] = make_uint2(pay, (unsigned)h);
    } else {
        int j = i - EE;
        if (j < NNZI){
            int r = irows[j]; if ((unsigned)r >= NUSR) return;
            unsigned c = (unsigned)icols[j]; if (c >= NENT) c = 0;
            unsigned bits = __float_as_uint(ivals[j]);
            unsigned rb = bits + 0x7FFFu + ((bits >> 16) & 1u);   // RNE to bf16
            unsigned pay = c | (((rb >> 16) & 0x7FFFu) << 17);
            int b = r >> 9;
            unsigned bb = rsdeg_u[b << 9] & 0xFFFFFu;
            unsigned slot = bb + (unsigned)atomicAdd(&bcur[NB_E + b], 1);
            if (slot < NNZI) bin_u[slot] = make_uint2(pay, (unsigned)r);
        }
    }
}

// ---------------------------------------------------------------- binned scatter pass 2 (L2-local place)
__global__ void k_scat2(const uint2* __restrict__ bin_e, const uint2* __restrict__ bin_u,
                        const unsigned* __restrict__ rsdeg_e, const unsigned* __restrict__ rsdeg_u,
                        int* cur_e, int* cur_u, unsigned* epk, unsigned* upk){
    int i = blockIdx.x*256 + threadIdx.x;
    if (i < EE){
        uint2 v = bin_e[i];
        unsigned h = v.y; if (h >= NENT) h = 0;
        unsigned slot = (rsdeg_e[h] & 0x1FFFFFu) + (unsigned)atomicAdd(&cur_e[h], 1);
        if (slot < EE) epk[slot] = v.x;
    } else {
        int j = i - EE;
        if (j < NNZI){
            uint2 v = bin_u[j];
            unsigned r = v.y; if (r >= NUSR) r = 0;
            unsigned slot = (rsdeg_u[r] & 0xFFFFFu) + (unsigned)atomicAdd(&cur_u[r], 1);
            if (slot < NNZI) upk[slot] = v.x;
        }
    }
}

// ---------------------------------------------------------------- direct scatter (small-ws fallback)
__global__ void k_scat_direct(const int* __restrict__ head, const int* __restrict__ tail,
                              const int* __restrict__ etype, const int* __restrict__ cate,
                              const int* __restrict__ irows, const int* __restrict__ icols,
                              const float* __restrict__ ivals,
                              int* cur_e, int* cur_u,
                              const unsigned* __restrict__ rsdeg_e, const unsigned* __restrict__ rsdeg_u,
                              unsigned* epk, unsigned* upk){
    int i = blockIdx.x*256 + threadIdx.x;
    if (i < EE){
        int h = head[i]; if ((unsigned)h >= NENT) return;
        unsigned tu = (unsigned)tail[i]; if (tu >= NENT) tu = 0;
        unsigned slot = (rsdeg_e[h] & 0x1FFFFFu) + (unsigned)atomicAdd(&cur_e[h], 1);
        unsigned ty = (unsigned)(etype[i] - 1) & 15u;
        unsigned cd = (unsigned)(cate[tu]  - 1) & 31u;
        if (slot < EE) epk[slot] = tu | (ty << 17) | (cd << 21);
    } else {
        int j = i - EE;
        if (j < NNZI){
            int r = irows[j]; if ((unsigned)r >= NUSR) return;
            unsigned c = (unsigned)icols[j]; if (c >= NENT) c = 0;
            unsigned slot = (rsdeg_u[r] & 0xFFFFFu) + (unsigned)atomicAdd(&cur_u[r], 1);
            unsigned bits = __float_as_uint(ivals[j]);
            unsigned rb = bits + 0x7FFFu + ((bits >> 16) & 1u);
            if (slot < NNZI) upk[slot] = c | (((rb >> 16) & 0x7FFFu) << 17);
        }
    }
}

// ---------------------------------------------------------------- latent path (both branches, LDS-staged)
__global__ void k_lat2(LatArgs A0, LatArgs A1){
    LatArgs a = (blockIdx.x == 0) ? A0 : A1;
    const int R = a.R;
    __shared__ float sW1[64*64], sW2[64*64];
    __shared__ float swt[R2_*64], wp[R2_*64];
    __shared__ float lf[NF_*64], lp1[NF_*64], lp2[NF_*64];
    __shared__ float Praw[64*NF_], qv[NF_];
    __shared__ float srp[NF_*R2_], zz[NF_*R2_];
    __shared__ float latls[NF_*64], norms[NF_];
    int t = threadIdx.x;

    for (int idx = t; idx < 64*64; idx += 256){ sW1[idx] = a.W1[idx]; sW2[idx] = a.W2[idx]; }
    for (int idx = t; idx < R*64; idx += 256) swt[idx] = a.wt[idx];
    lf[t] = fin(a.lin[t]);
    __syncthreads();

    {
        int f = t >> 6, k = t & 63;
        float s1 = a.b1[k], s2 = a.b2[k];
        for (int c = 0; c < 64; c++){
            float lv = lf[f*64+c];
            s1 += lv * sW1[c*64+k];
            s2 += lv * sW2[c*64+k];
        }
        lp1[t] = s1; lp2[t] = s2;
    }
    __syncthreads();

    {
        int c = t >> 2, f = t & 3;
        float s = 0.f;
        for (int k = 0; k < 64; k++) s += sW1[c*64+k] * lp1[f*64+k];
        Praw[c*4+f] = s;
    }
    if (t < NF_){
        float s = 0.f;
        for (int k = 0; k < 64; k++) s += a.b1[k] * lp1[t*64+k];
        qv[t] = s;
    }
    __syncthreads();

    {
        int g = t >> 6, c = t & 63;
        float s = 0.f;
        for (int f = 0; f < NF_; f++) s += Praw[c*4+f] * a.Wua[f*4+g];
        a.P2[g*64+c] = s;
    }
    if (t < NF_){
        float s = a.bua[t];
        for (int f = 0; f < NF_; f++) s += qv[f] * a.Wua[f*4+t];
        a.q2[t] = s;
    }
    for (int idx = t; idx < R*64; idx += 256){
        int r = idx >> 6, k = idx & 63;
        float s = a.b2[k];
        for (int c = 0; c < 64; c++) s += swt[r*64+c] * sW2[c*64+k];
        wp[idx] = s;
    }
    __syncthreads();

    if (t < NF_*R){
        int f = t / R, r = t % R;
        float s = 0.f;
        for (int k = 0; k < 64; k++) s += lp2[f*64+k] * wp[r*64+k];
        srp[f*R2_ + r] = s;
    }
    __syncthreads();

    if (t < NF_*R){
        int f = t / R, ss = t % R;
        float v = a.bwa[ss];
        for (int r = 0; r < R; r++) v += srp[f*R2_ + r] * a.Wwa[r*R + ss];
        zz[f*R2_ + ss] = (v > 0.f) ? v : 0.2f*v;
    }
    __syncthreads();

    if (t < NF_){
        float m = -1e30f;
        for (int r = 0; r < R; r++) m = fmaxf(m, zz[t*R2_ + r]);
        float sum = 0.f;
        for (int r = 0; r < R; r++){ float e = expf(zz[t*R2_ + r] - m); zz[t*R2_ + r] = e; sum += e; }
        float inv = 1.f / sum;
        for (int r = 0; r < R; r++) zz[t*R2_ + r] *= inv;
    }
    __syncthreads();

    {
        int f = t >> 6, c = t & 63;
        float s = 0.f;
        for (int r = 0; r < R; r++) s += zz[f*R2_ + r] * swt[r*64 + c];
        latls[t] = s; a.lat[t] = s;
    }
    __syncthreads();
    if (t < NF_){
        float s = 0.f;
        for (int c = 0; c < 64; c++){ float v = latls[t*64+c]; s += v*v; }
        norms[t] = fmaxf(sqrtf(s), 1e-12f);
    }
    __syncthreads();
    a.nlat[t] = latls[t] / norms[t >> 6];
}

// ---------------------------------------------------------------- entity agg core
template<typename SRC>
__device__ __forceinline__ float ent_row(const SRC* __restrict__ e_src, const float* wl,
                                         const unsigned* __restrict__ epk,
                                         unsigned rd, int use_d, int lane){
    int s = (int)(rd & 0x1FFFFFu);
    int deg = (int)(rd >> 21);
    int e_ = s + deg;
    float acc = 0.f;
    int k = s;
    for (; k + 4 <= e_; k += 4){
        unsigned p0 = epk[k], p1 = epk[k+1], p2 = epk[k+2], p3 = epk[k+3];
        unsigned t0 = p0 & 0x1FFFFu; t0 = t0 < NENT ? t0 : 0u;
        unsigned t1 = p1 & 0x1FFFFu; t1 = t1 < NENT ? t1 : 0u;
        unsigned t2 = p2 & 0x1FFFFu; t2 = t2 < NENT ? t2 : 0u;
        unsigned t3 = p3 & 0x1FFFFu; t3 = t3 < NENT ? t3 : 0u;
        float g0 = ldv(e_src, (long long)t0*64 + lane);
        float g1 = ldv(e_src, (long long)t1*64 + lane);
        float g2 = ldv(e_src, (long long)t2*64 + lane);
        float g3 = ldv(e_src, (long long)t3*64 + lane);
        int w0 = use_d ? (int)((p0 >> 21) & 31u) : (int)((p0 >> 17) & 15u);
        int w1 = use_d ? (int)((p1 >> 21) & 31u) : (int)((p1 >> 17) & 15u);
        int w2 = use_d ? (int)((p2 >> 21) & 31u) : (int)((p2 >> 17) & 15u);
        int w3 = use_d ? (int)((p3 >> 21) & 31u) : (int)((p3 >> 17) & 15u);
        acc += g0*wl[w0*64+lane] + g1*wl[w1*64+lane] + g2*wl[w2*64+lane] + g3*wl[w3*64+lane];
    }
    for (; k < e_; k++){
        unsigned p = epk[k];
        unsigned ti = p & 0x1FFFFu; ti = ti < NENT ? ti : 0u;
        int wi = use_d ? (int)((p >> 21) & 31u) : (int)((p >> 17) & 15u);
        acc += ldv(e_src, (long long)ti*64 + lane) * wl[wi*64+lane];
    }
    float ea = fin(acc) / fmaxf((float)deg, 1.f);
    float sq = ea*ea;
    for (int m = 1; m < 64; m <<= 1) sq += __shfl_xor(sq, m, 64);
    float nrm = fmaxf(sqrtf(fin(sq)), 1e-12f);
    return ea / nrm;
}

template<typename ESRC>
__global__ __launch_bounds__(256) void k_ent0(const ESRC* __restrict__ e_src,
                                              const float* __restrict__ wtab, int R, int use_d,
                                              const unsigned* __restrict__ rsdeg_e,
                                              const unsigned* __restrict__ epk,
                                              bf16* dst){
    __shared__ float wl[R2_*64];
    int t = threadIdx.x;
    for (int idx = t; idx < R2_*64; idx += 256)
        wl[idx] = (idx < R*64) ? wtab[idx] : 0.f;
    __syncthreads();
    int ent = blockIdx.x*4 + (t >> 6);
    int lane = t & 63;
    if (ent >= NENT) return;
    float v = ent_row(e_src, wl, epk, rsdeg_e[ent], use_d, lane);
    dst[(long long)ent*64 + lane] = f2b(v);
}

// iter-1 fused residual: out(fp32) = base + self(iter1) + normalized row
__global__ __launch_bounds__(256) void k_ent1f(const bf16* __restrict__ e_src,
                                               const float* __restrict__ base_emb,
                                               const float* __restrict__ wtab, int R, int use_d,
                                               const unsigned* __restrict__ rsdeg_e,
                                               const unsigned* __restrict__ epk,
                                               float* dst){
    __shared__ float wl[R2_*64];
    int t = threadIdx.x;
    for (int idx = t; idx < R2_*64; idx += 256)
        wl[idx] = (idx < R*64) ? wtab[idx] : 0.f;
    __syncthreads();
    int ent = blockIdx.x*4 + (t >> 6);
    int lane = t & 63;
    if (ent >= NENT) return;
    float v = ent_row(e_src, wl, epk, rsdeg_e[ent], use_d, lane);
    long long ix = (long long)ent*64 + lane;
    dst[ix] = base_emb[ix] + b2f(e_src[ix]) + v;
}

// ---------------------------------------------------------------- user agg pieces
template<typename ESRC>
__device__ __forceinline__ float usr_gather(const ESRC* __restrict__ e_src,
                                            const unsigned* __restrict__ upk,
                                            unsigned rd, int lane){
    int s = (int)(rd & 0xFFFFFu);
    int e_ = s + (int)(rd >> 20);
    float acc = 0.f;
    int k = s;
    for (; k + 4 <= e_; k += 4){
        unsigned p0 = upk[k], p1 = upk[k+1], p2 = upk[k+2], p3 = upk[k+3];
        unsigned c0 = p0 & 0x1FFFFu; c0 = c0 < NENT ? c0 : 0u;
        unsigned c1 = p1 & 0x1FFFFu; c1 = c1 < NENT ? c1 : 0u;
        unsigned c2 = p2 & 0x1FFFFu; c2 = c2 < NENT ? c2 : 0u;
        unsigned c3 = p3 & 0x1FFFFu; c3 = c3 < NENT ? c3 : 0u;
        float v0 = __uint_as_float(((p0 >> 17) & 0x7FFFu) << 16);
        float v1 = __uint_as_float(((p1 >> 17) & 0x7FFFu) << 16);
        float v2 = __uint_as_float(((p2 >> 17) & 0x7FFFu) << 16);
        float v3 = __uint_as_float(((p3 >> 17) & 0x7FFFu) << 16);
        acc += v0*ldv(e_src,(long long)c0*64+lane) + v1*ldv(e_src,(long long)c1*64+lane)
             + v2*ldv(e_src,(long long)c2*64+lane) + v3*ldv(e_src,(long long)c3*64+lane);
    }
    for (; k < e_; k++){
        unsigned p = upk[k];
        unsigned c = p & 0x1FFFFu; c = c < NENT ? c : 0u;
        float v = __uint_as_float(((p >> 17) & 0x7FFFu) << 16);
        acc += v * ldv(e_src, (long long)c*64 + lane);
    }
    return fin(acc);
}

__device__ __forceinline__ float usr_epi(float acc, float x,
                                         const float* P2l, const float* latl, const float* q2l,
                                         int lane){
    float s0 = x*P2l[lane], s1 = x*P2l[64+lane], s2 = x*P2l[128+lane], s3 = x*P2l[192+lane];
    for (int m = 1; m < 64; m <<= 1){
        s0 += __shfl_xor(s0, m, 64);
        s1 += __shfl_xor(s1, m, 64);
        s2 += __shfl_xor(s2, m, 64);
        s3 += __shfl_xor(s3, m, 64);
    }
    s0 += q2l[0]; s1 += q2l[1]; s2 += q2l[2]; s3 += q2l[3];
    s0 = (s0 > 0.f) ? s0 : 0.2f*s0;
    s1 = (s1 > 0.f) ? s1 : 0.2f*s1;
    s2 = (s2 > 0.f) ? s2 : 0.2f*s2;
    s3 = (s3 > 0.f) ? s3 : 0.2f*s3;
    float mx = fmaxf(fmaxf(s0, s1), fmaxf(s2, s3));
    float e0 = expf(s0-mx), e1 = expf(s1-mx), e2 = expf(s2-mx), e3 = expf(s3-mx);
    float inv = 1.f / (e0+e1+e2+e3);
    float mix = fin((e0*latl[lane] + e1*latl[64+lane] + e2*latl[128+lane] + e3*latl[192+lane]) * inv);
    float ua = acc * (1.f + mix);
    float sq = ua*ua;
    for (int m = 1; m < 64; m <<= 1) sq += __shfl_xor(sq, m, 64);
    float nrm = fmaxf(sqrtf(fin(sq)), 1e-12f);
    return ua / nrm;
}

// iter-0 fused: ONE gather (segment sum identical for both branches), two epilogues
template<typename ESRC>
__global__ __launch_bounds__(256) void k_usr0f2(const float* __restrict__ u_src,
                                                const ESRC* __restrict__ e_src,
                                                const unsigned* __restrict__ rsdeg_u,
                                                const unsigned* __restrict__ upk,
                                                const float* __restrict__ P2c,
                                                const float* __restrict__ q2c,
                                                const float* __restrict__ latc,
                                                const float* __restrict__ P2d,
                                                const float* __restrict__ q2d,
                                                const float* __restrict__ latd,
                                                float* __restrict__ dst_c,
                                                float* __restrict__ dst_d){
    __shared__ float P2lc[NF_*64], latlc[NF_*64], P2ld[NF_*64], latld[NF_*64];
    __shared__ float q2lc[NF_], q2ld[NF_];
    int t = threadIdx.x;
    P2lc[t] = fin(P2c[t]); latlc[t] = fin(latc[t]);
    P2ld[t] = fin(P2d[t]); latld[t] = fin(latd[t]);
    if (t < NF_){ q2lc[t] = fin(q2c[t]); q2ld[t] = fin(q2d[t]); }
    __syncthreads();
    int u = blockIdx.x*4 + (t >> 6);
    int lane = t & 63;
    if (u >= NUSR) return;
    float acc = usr_gather(e_src, upk, rsdeg_u[u], lane);
    long long ix = (long long)u*64 + lane;
    float x = u_src[ix];
    dst_c[ix] = usr_epi(acc, x, P2lc, latlc, q2lc, lane);
    dst_d[ix] = usr_epi(acc, x, P2ld, latld, q2ld, lane);
}

// iter-1 fused residual, in-place on the fp32 out region
__global__ __launch_bounds__(256) void k_usr1f(float* u_io,
                                               const bf16* __restrict__ e_src,
                                               const float* __restrict__ base_emb,
                                               const unsigned* __restrict__ rsdeg_u,
                                               const unsigned* __restrict__ upk,
                                               const float* __restrict__ P2,
                                               const float* __restrict__ q2,
                                               const float* __restrict__ lat_new){
    __shared__ float P2l[NF_*64], latl[NF_*64], q2l[NF_];
    int t = threadIdx.x;
    P2l[t] = fin(P2[t]); latl[t] = fin(lat_new[t]);
    if (t < NF_) q2l[t] = fin(q2[t]);
    __syncthreads();
    int u = blockIdx.x*4 + (t >> 6);
    int lane = t & 63;
    if (u >= NUSR) return;
    float acc = usr_gather(e_src, upk, rsdeg_u[u], lane);
    long long ix = (long long)u*64 + lane;
    float x = u_io[ix];
    float v = usr_epi(acc, x, P2l, latl, q2l, lane);
    u_io[ix] = base_emb[ix] + x + v;
}

// ---------------------------------------------------------------- distance correlation (2 blocks)
__global__ void k_cor(const float* __restrict__ latn1_c,
                      const float* __restrict__ ldiv,
                      const float* __restrict__ nld0, const float* __restrict__ nld1,
                      float* out){
    __shared__ float rows[NF_*64];
    __shared__ float nr[NF_];
    __shared__ float t1s[64], t2s[64], m1s[64], m2s[64];
    __shared__ float pr[256], pr2[256], pr3[256];
    __shared__ float gms[2];
    __shared__ float corsh;
    int t = threadIdx.x, b = blockIdx.x;

    if (b == 0){
        rows[t] = fin(latn1_c[t]);
        __syncthreads();
        if (t < NF_){
            float s = 0.f;
            for (int c = 0; c < 64; c++){ float v = rows[t*64+c]; s += v*v; }
            nr[t] = fmaxf(sqrtf(s), 1e-12f);
        }
        __syncthreads();
        float v = rows[t];
        __syncthreads();
        rows[t] = v + v / nr[t >> 6];
    } else {
        rows[t] = ldiv[t] + fin(nld0[t]) + fin(nld1[t]);
    }
    if (t == 0) corsh = 0.f;
    __syncthreads();

    for (int i = 0; i < NF_; i++) for (int j = i+1; j < NF_; j++){
        if (t < 64){ t1s[t] = rows[i*64+t]; t2s[t] = rows[j*64+t]; }
        __syncthreads();
        int i_ = t >> 2, q = t & 3;
        float pa = 0.f, pb = 0.f;
        for (int jj = q*16; jj < q*16+16; jj++){
            float d1 = t1s[i_] - t1s[jj]; pa += sqrtf(fmaxf(d1*d1, 0.f) + 1e-8f);
            float d2 = t2s[i_] - t2s[jj]; pb += sqrtf(fmaxf(d2*d2, 0.f) + 1e-8f);
        }
        pr[t] = pa; pr2[t] = pb;
        __syncthreads();
        if (q == 0){
            m1s[i_] = (pr[t] + pr[t+1] + pr[t+2] + pr[t+3]) / 64.f;
            m2s[i_] = (pr2[t] + pr2[t+1] + pr2[t+2] + pr2[t+3]) / 64.f;
        }
        __syncthreads();
        if (t == 0){
            float s1 = 0.f, s2 = 0.f;
            for (int ii = 0; ii < 64; ii++){ s1 += m1s[ii]; s2 += m2s[ii]; }
            gms[0] = s1 / 64.f; gms[1] = s2 / 64.f;
        }
        __syncthreads();
        float gm1 = gms[0], gm2 = gms[1];
        float sab = 0.f, saa = 0.f, sbb = 0.f;
        for (int kk = 0; kk < 16; kk++){
            int idx = t*16 + kk; int ii = idx >> 6, jj = idx & 63;
            float d1 = t1s[ii] - t1s[jj];
            float A = sqrtf(fmaxf(d1*d1, 0.f) + 1e-8f) - m1s[ii] - m1s[jj] + gm1;
            float d2 = t2s[ii] - t2s[jj];
            float B = sqrtf(fmaxf(d2*d2, 0.f) + 1e-8f) - m2s[ii] - m2s[jj] + gm2;
            sab += A*B; saa += A*A; sbb += B*B;
        }
        pr[t] = sab; pr2[t] = saa; pr3[t] = sbb;
        __syncthreads();
        for (int off = 128; off; off >>= 1){
            if (t < off){ pr[t] += pr[t+off]; pr2[t] += pr2[t+off]; pr3[t] += pr3[t+off]; }
            __syncthreads();
        }
        if (t == 0){
            float dab = sqrtf(fmaxf(pr[0]/4096.f, 0.f) + 1e-8f);
            float daa = sqrtf(fmaxf(pr2[0]/4096.f, 0.f) + 1e-8f);
            float dbb = sqrtf(fmaxf(pr3[0]/4096.f, 0.f) + 1e-8f);
            corsh += dab / sqrtf(daa*dbb + 1e-8f);
        }
        __syncthreads();
    }
    if (t == 0){
        long long pos = (b == 0) ? 9600000LL : 19200001LL;
        out[pos] = corsh;
    }
}

// ================================================================ host
extern "C" void kernel_launch(void* const* d_in, const int* in_sizes, int n_in,
                              void* d_out, int out_size, void* d_ws, size_t ws_size,
                              hipStream_t stream){
    const float* user_emb   = (const float*)d_in[0];
    const float* entity_emb = (const float*)d_in[1];
    const float* latent_emb = (const float*)d_in[2];
    const float* latent_div = (const float*)d_in[3];
    const float* weight     = (const float*)d_in[4];
    const float* weight_d   = (const float*)d_in[5];
    const float* cW1 = (const float*)d_in[6];  const float* cb1 = (const float*)d_in[7];
    const float* cW2 = (const float*)d_in[8];  const float* cb2 = (const float*)d_in[9];
    const float* cWua= (const float*)d_in[10]; const float* cbua= (const float*)d_in[11];
    const float* cWwa= (const float*)d_in[12]; const float* cbwa= (const float*)d_in[13];
    const float* eW1 = (const float*)d_in[14]; const float* eb1 = (const float*)d_in[15];
    const float* eW2 = (const float*)d_in[16]; const float* eb2 = (const float*)d_in[17];
    const float* eWua= (const float*)d_in[18]; const float* ebua= (const float*)d_in[19];
    const float* eWwa= (const float*)d_in[20]; const float* ebwa= (const float*)d_in[21];
    const float* ivals = (const float*)d_in[22];
    const int* edge_index = (const int*)d_in[23];
    const int* etype      = (const int*)d_in[24];
    const int* cate       = (const int*)d_in[25];
    const int* irows      = (const int*)d_in[26];
    const int* icols      = (const int*)d_in[27];
    float* out = (float*)d_out;

    const int* head = edge_index;
    const int* tail = edge_index + EE;

    // ---- workspace carve
    char* base = (char*)d_ws;
    size_t off = 0;
    auto carve = [&](size_t bytes) -> void* {
        void* p = base + off;
        off += (bytes + 255) & ~(size_t)255;
        return p;
    };
    unsigned* rsdeg_e = (unsigned*)carve((size_t)NENT*4);
    unsigned* rsdeg_u = (unsigned*)carve((size_t)NUSR*4);
    unsigned* epk     = (unsigned*)carve((size_t)EE*4);
    unsigned* upk     = (unsigned*)carve((size_t)NNZI*4);
    int* deg_e = (int*)carve((size_t)NENT*4);
    int* deg_u = (int*)carve((size_t)NUSR*4);
    int* cur_e = (int*)carve((size_t)NENT*4);
    int* cur_u = (int*)carve((size_t)NUSR*4);
    int* part  = (int*)carve(NCH*4);
    int* bcur  = (int*)carve((NB_E+NB_U)*4);
    float* latn[2][2]; float* nlat[2][2]; float* P2b[2][2]; float* q2b[2][2];
    for (int b = 0; b < 2; b++) for (int i = 0; i < 2; i++){
        latn[b][i] = (float*)carve(NF_*64*4);
        nlat[b][i] = (float*)carve(NF_*64*4);
        P2b [b][i] = (float*)carve(NF_*64*4);
        q2b [b][i] = (float*)carve(64);
    }
    size_t common = off;
    const size_t ebuf = (size_t)NENT*CC*2;               // 12.8 MB
    const size_t al = 256;
    auto pad = [&](size_t b){ return (b + al - 1) & ~(al - 1); };

    // tiers: S = ebf + eA (bins alias both); C = eA + dedicated bin_u (bin_e aliases eA);
    //        D = eA only, direct scatter; else sentinel
    int tier;
    bf16 *ebf = nullptr, *eA = nullptr;
    uint2 *bin_e = nullptr, *bin_u = nullptr;
    if (ws_size >= common + 2*pad(ebuf)){
        ebf = (bf16*)carve(ebuf);
        eA  = (bf16*)carve(ebuf);
        bin_e = (uint2*)eA;           // 12.0 MB <= 12.8, consumed before eA written
        bin_u = (uint2*)ebf;          // 8.0 MB <= 12.8, consumed before k_conv writes ebf
        tier = 0;
    } else if (ws_size >= common + pad(ebuf) + pad((size_t)NNZI*8)){
        eA  = (bf16*)carve(ebuf);
        bin_u = (uint2*)carve((size_t)NNZI*8);
        bin_e = (uint2*)eA;
        tier = 1;
    } else if (ws_size >= common + pad(ebuf)){
        eA = (bf16*)carve(ebuf);
        tier = 2;
    } else {
        k_sentinel<<<1, 256, 0, stream>>>(out, 10000.f + (float)(ws_size >> 20));
        return;
    }

    float* oe_c = out;
    float* ou_c = out + 6400000LL;
    float* oe_d = out + 9600001LL;
    float* ou_d = out + 16000001LL;

    // ---- CSR build with ordered scan
    k_init<<<(NENT+255)/256, 256, 0, stream>>>(deg_e, deg_u, cur_e, cur_u, bcur);
    int gh = (EE + NNZI + 255)/256;
    k_hist<<<gh, 256, 0, stream>>>(head, irows, deg_e, deg_u);
    k_scan1<<<NCH, 256, 0, stream>>>(deg_e, deg_u, part);
    k_scan2<<<1, 64, 0, stream>>>(part);
    k_scan3<<<NCH, 256, 0, stream>>>(deg_e, deg_u, part, rsdeg_e, rsdeg_u);
    if (tier <= 1){
        k_scat1<<<gh, 256, 0, stream>>>(head, tail, etype, cate, irows, icols, ivals,
                                        rsdeg_e, rsdeg_u, bcur, bin_e, bin_u);
        k_scat2<<<gh, 256, 0, stream>>>(bin_e, bin_u, rsdeg_e, rsdeg_u, cur_e, cur_u, epk, upk);
    } else {
        k_scat_direct<<<gh, 256, 0, stream>>>(head, tail, etype, cate, irows, icols, ivals,
                                              cur_e, cur_u, rsdeg_e, rsdeg_u, epk, upk);
    }
    if (tier == 0) k_conv<<<(NENT*CC+255)/256, 256, 0, stream>>>(entity_emb, ebf);

    // ---- latent path
    LatArgs a_c0 = {latent_emb, cW1, cb1, cW2, cb2, cWua, cbua, cWwa, cbwa, weight,
                    latn[0][0], nlat[0][0], P2b[0][0], q2b[0][0], R1_};
    LatArgs a_d0 = {latent_div, eW1, eb1, eW2, eb2, eWua, ebua, eWwa, ebwa, weight_d,
                    latn[1][0], nlat[1][0], P2b[1][0], q2b[1][0], R2_};
    k_lat2<<<2, 256, 0, stream>>>(a_c0, a_d0);
    LatArgs a_c1 = {latn[0][0], cW1+4096, cb1+64, cW2+4096, cb2+64, cWua+16, cbua+4,
                    cWwa+R1_*R1_, cbwa+R1_, weight,
                    latn[0][1], nlat[0][1], P2b[0][1], q2b[0][1], R1_};
    LatArgs a_d1 = {nlat[1][0], eW1+4096, eb1+64, eW2+4096, eb2+64, eWua+16, ebua+4,
                    eWwa+R2_*R2_, ebwa+R2_, weight_d,
                    latn[1][1], nlat[1][1], P2b[1][1], q2b[1][1], R2_};
    k_lat2<<<2, 256, 0, stream>>>(a_c1, a_d1);

    int ge = (NENT+3)/4, gu = (NUSR+3)/4;

    // ---- user iter-0, fused across branches (identical segment sum)
    if (tier == 0)
        k_usr0f2<bf16><<<gu, 256, 0, stream>>>(user_emb, ebf, rsdeg_u, upk,
            P2b[0][0], q2b[0][0], latn[0][0], P2b[1][0], q2b[1][0], latn[1][0], ou_c, ou_d);
    else
        k_usr0f2<float><<<gu, 256, 0, stream>>>(user_emb, entity_emb, rsdeg_u, upk,
            P2b[0][0], q2b[0][0], latn[0][0], P2b[1][0], q2b[1][0], latn[1][0], ou_c, ou_d);

    // ---- per-branch entity iter-0 + fused iter-1 (shared eA)
    const float* wts[2] = {weight, weight_d};
    const int    Rs[2]  = {R1_, R2_};
    float* oes[2] = {oe_c, oe_d};
    float* ous[2] = {ou_c, ou_d};
    for (int br = 0; br < 2; br++){
        if (tier == 0)
            k_ent0<bf16><<<ge, 256, 0, stream>>>(ebf, wts[br], Rs[br], br, rsdeg_e, epk, eA);
        else
            k_ent0<float><<<ge, 256, 0, stream>>>(entity_emb, wts[br], Rs[br], br, rsdeg_e, epk, eA);
        k_ent1f<<<ge, 256, 0, stream>>>(eA, entity_emb, wts[br], Rs[br], br, rsdeg_e, epk, oes[br]);
        k_usr1f<<<gu, 256, 0, stream>>>(ous[br], eA, user_emb, rsdeg_u, upk,
            P2b[br][1], q2b[br][1], latn[br][1]);
    }

    // ---- distance correlations
    k_cor<<<2, 256, 0, stream>>>(latn[0][1], latent_div, nlat[1][0], nlat[1][1], out);
}